// Round 12
// baseline (458.243 us; speedup 1.0000x reference)
//
#include <hip/hip_runtime.h>
#include <math.h>
#include <stdint.h>

#define BATCH 64
#define T 256
#define NF 64
#define H 128
#define H4 512                    // 4*H
#define HP1 129
#define WF_STRIDE (HP1 * H4)      // 66048 floats per feature
#define FEATS (NF * H + H)        // 8320
#define NTH 1024                  // 16 waves

// rec layout: per (f, tid) an 80-byte record = 4 weight uint4 + 1 hdr uint4.
// weights: same semantics as R11's pack (absmax-0-verified); hdr = {wx f32,
// bias0..3 as 4 fp16, pad}. 64*1024*80 = 5 MB.
#define REC_BYTES ((size_t)NF * 1024 * 80)

typedef float vf2 __attribute__((ext_vector_type(2)));

__device__ __forceinline__ float sigmoidf_(float x) {
    return 1.0f / (1.0f + __expf(-x));
}

__device__ __forceinline__ float tanhf_(float x) {
    float ax = fabsf(x);
    float e = __expf(2.0f * ax);              // inf for large ax -> r = 1
    float r = 1.0f - 2.0f / (e + 1.0f);
    return copysignf(r, x);
}

// decode 2 fp8 bytes of a dword -> float2 (HI must be literal)
template<bool HI>
__device__ __forceinline__ vf2 dec2f(unsigned u) {
    return __builtin_amdgcn_cvt_pk_f32_fp8(u, HI);
}

#define WAITV(N) do { asm volatile("s_waitcnt vmcnt(" #N ")" ::: "memory"); \
                      __builtin_amdgcn_sched_barrier(0); } while (0)
#define BARRIER() do { asm volatile("s_waitcnt lgkmcnt(0)" ::: "memory"); \
                       __builtin_amdgcn_s_barrier(); \
                       asm volatile("" ::: "memory"); } while (0)

// ===== repack5: W_lin h-rows -> fp8 (x4096) + hdr, 80B per-thread records ====
// thread (f, tid): kh=tid>>9, c=tid&511. Weight uint4 i: h=i>>1, q=i&1,
// k0=h*64+kh*32+q*16; byte r of dword w <-> k=k0+4w+r, col c,
// val = fp8_e4m3(W_lin[f][1+k][c]*4096)  [R11 semantics, verified].
// hdr: {wx = kh==0 ? W_lin[f][0][c] : 0;  bias g = b_lin[f][g*H + tid] as fp16
// (tid<128 only, else 0); pad}.
__global__ __launch_bounds__(256)
void repack5_kernel(const float* __restrict__ W_lin, const float* __restrict__ b_lin,
                    uint4* __restrict__ rec) {
    const int lin = blockIdx.x * 256 + threadIdx.x;   // 0..65535
    const int tid = lin & 1023;
    const int f   = lin >> 10;
    const int kh  = tid >> 9;
    const int cc  = tid & 511;
    uint4* orec = rec + (size_t)lin * 5;
    #pragma unroll
    for (int i = 0; i < 4; ++i) {
        const int h  = i >> 1;
        const int q  = i & 1;
        const int k0 = h * 64 + kh * 32 + q * 16;
        const float* src = W_lin + (size_t)f * WF_STRIDE + (size_t)(1 + k0) * H4 + cc;
        unsigned u[4];
        #pragma unroll
        for (int w = 0; w < 4; ++w) {
            const float v0 = src[(4 * w + 0) * H4] * 4096.0f;
            const float v1 = src[(4 * w + 1) * H4] * 4096.0f;
            const float v2 = src[(4 * w + 2) * H4] * 4096.0f;
            const float v3 = src[(4 * w + 3) * H4] * 4096.0f;
            unsigned r = 0;
            r = __builtin_amdgcn_cvt_pk_fp8_f32(v0, v1, r, false);
            r = __builtin_amdgcn_cvt_pk_fp8_f32(v2, v3, r, true);
            u[w] = r;
        }
        uint4 o; o.x = u[0]; o.y = u[1]; o.z = u[2]; o.w = u[3];
        orec[i] = o;
    }
    // hdr
    union { uint4 u; float fv[4]; _Float16 hf[8]; } hd;
    hd.u = make_uint4(0, 0, 0, 0);
    hd.fv[0] = (kh == 0) ? W_lin[(size_t)f * WF_STRIDE + cc] : 0.0f;
    if (tid < H) {
        const float* bb = b_lin + f * H4 + tid;
        hd.hf[2] = (_Float16)bb[0];
        hd.hf[3] = (_Float16)bb[H];
        hd.hf[4] = (_Float16)bb[2 * H];
        hd.hf[5] = (_Float16)bb[3 * H];
    }
    orec[4] = hd.u;
}

// ===== main scan: R11 skeleton + asm-pinned VGPR double-buffer ==============
// 5 inline-asm global_load_dwordx4 per step ("=&v" -> VGPR class, compiler
// CANNOT AGPRize or sink them; R2/R3/R11 all showed compiler-held buffers get
// AGPRized with an in-step vmcnt drain). The ONLY vmem wait is a counted
// vmcnt(5) at the consume point one full step after issue. Zero compiler vmem
// in the loop (bias/wx ride in the record), raw s_barrier+lgkmcnt (no vmcnt
// drain). Math identical to R11 (absmax-0-verified).
__global__ __launch_bounds__(NTH, 2)
void lstm_scan_fp8_v3(const float* __restrict__ X,
                      const int* __restrict__ lengths,
                      const float* __restrict__ W_dec,
                      const float* __restrict__ b_dec,
                      const float* __restrict__ W_out,
                      const float* __restrict__ b_out,
                      const uint4* __restrict__ rec,
                      float* __restrict__ out)
{
    __shared__ float s_feats[FEATS];          // [0,H)=c_t, [H,..)=h_t row-major
    __shared__ float s_inp[H];                // decayed hidden row (f32)
    __shared__ float s_part[2][H4];           // K-half matvec partials
    __shared__ float s_X[4 * T];
    __shared__ float s_wdec[NF];
    __shared__ float s_bdec[NF];
    __shared__ float s_red[32];

    float* s_ct = s_feats;
    float* s_ht = s_feats + H;

    const int tid = threadIdx.x;
    const int b   = blockIdx.x;
    const int c   = tid & 511;                // gate column
    const int kh  = tid >> 9;                 // K half (0/1), wave-uniform

    const float* Xb = X + b * 4 * T;
    const int len = lengths[b];

    for (int i = tid; i < NF * H; i += NTH) s_ht[i] = 0.0f;
    for (int i = tid; i < 4 * T; i += NTH) s_X[i] = Xb[i];
    if (tid < NF) { s_wdec[tid] = W_dec[tid]; s_bdec[tid] = b_dec[tid]; }
    if (tid < H) s_inp[tid] = 0.0f;
    __syncthreads();

    float c_t = 0.0f, accs = 0.0f, cnts = 0.0f;

    // issue 5 asm loads for feature MF into R0..R4 (80B record, offsets 0..64)
    #define ISSUE5(MF, R0, R1, R2, R3, R4) do {                                 \
        const uint64_t ap = (uint64_t)(uintptr_t)((const char*)rec              \
                          + ((size_t)(MF) * 1024 + tid) * 80);                  \
        asm volatile("global_load_dwordx4 %0, %5, off\n\t"                      \
                     "global_load_dwordx4 %1, %5, off offset:16\n\t"            \
                     "global_load_dwordx4 %2, %5, off offset:32\n\t"            \
                     "global_load_dwordx4 %3, %5, off offset:48\n\t"            \
                     "global_load_dwordx4 %4, %5, off offset:64"                \
                     : "=&v"(R0), "=&v"(R1), "=&v"(R2), "=&v"(R3), "=&v"(R4)    \
                     : "v"(ap) : "memory");                                     \
    } while (0)

    // dot of one weight-uint4 (16 fp8 k's starting at K0) vs f32 input pairs
    // (wave-uniform LDS addresses -> broadcast reads)
    #define DOTF(W, K0) do {                                                    \
        const vf2* ip = (const vf2*)(s_inp + (K0));                             \
        vf2 d;                                                                  \
        d = dec2f<false>((W).x); acc += d * ip[0];                              \
        d = dec2f<true >((W).x); acc += d * ip[1];                              \
        d = dec2f<false>((W).y); acc += d * ip[2];                              \
        d = dec2f<true >((W).y); acc += d * ip[3];                              \
        d = dec2f<false>((W).z); acc += d * ip[4];                              \
        d = dec2f<true >((W).z); acc += d * ip[5];                              \
        d = dec2f<false>((W).w); acc += d * ip[6];                              \
        d = dec2f<true >((W).w); acc += d * ip[7];                              \
    } while (0)

    uint4 A0, A1, A2, A3, AH, B0, B1, B2, B3, BH;

    // prologue: issue step 0's record (5 outstanding)
    {
        const int m0 = (int)s_X[T];
        ISSUE5(m0, A0, A1, A2, A3, AH);
    }

    #define STEP(C0, C1, C2, C3, CH, N0, N1, N2, N3, NH)                        \
    {                                                                           \
        const int   mj  = (int)s_X[T + j];                                      \
        const float xj  = s_X[2 * T + j];                                       \
        const int   jn  = (j + 1 < T) ? (j + 1) : (T - 1);                      \
        const int   mjn = (int)s_X[T + jn];                                     \
        ISSUE5(mjn, N0, N1, N2, N3, NH);   /* 10 in flight */                   \
        WAITV(5);                          /* current step's 5 landed */        \
        vf2 acc; acc[0] = 0.0f; acc[1] = 0.0f;                                  \
        DOTF(C0, kh * 32);                                                      \
        DOTF(C1, kh * 32 + 16);                                                 \
        DOTF(C2, 64 + kh * 32);                                                 \
        DOTF(C3, 64 + kh * 32 + 16);                                            \
        union { uint4 u; float fv[4]; _Float16 hf[8]; } hu; hu.u = CH;          \
        float a = (acc[0] + acc[1]) * (1.0f / 4096.0f);                         \
        if (kh == 0) a = fmaf(xj, hu.fv[0], a);                                 \
        s_part[kh][c] = a;                                                      \
        BARRIER();  /* B: partials ready (vmcnt NOT drained) */                 \
        if (tid < H) {                                                          \
            const int h = tid;                                                  \
            const float gi = s_part[0][h]       + s_part[1][h]       + (float)hu.hf[2]; \
            const float gf = s_part[0][H + h]   + s_part[1][H + h]   + (float)hu.hf[3]; \
            const float go = s_part[0][2*H + h] + s_part[1][2*H + h] + (float)hu.hf[4]; \
            const float gc = s_part[0][3*H + h] + s_part[1][3*H + h] + (float)hu.hf[5]; \
            const float c_cand = sigmoidf_(gf) * c_t + sigmoidf_(gi) * tanhf_(gc); \
            const float h_row  = sigmoidf_(go) * tanhf_(c_cand);                \
            s_ht[mj * H + h] = h_row;                                           \
            accs += c_cand;                                                     \
            cnts += 1.0f;                                                       \
            const float tj = s_X[j];                                            \
            const float tn = (j < T - 1) ? s_X[j + 1] : (tj + 1.0f);            \
            const bool boundary = (j == len - 1) || (tn != tj);                 \
            if (boundary) { c_t = accs / fmaxf(cnts, 1.0f); accs = 0.0f; cnts = 0.0f; } \
            const float dn  = s_X[3 * T + jn];                                  \
            const float dmn = fmaf(s_wdec[mjn], dn, s_bdec[mjn]);               \
            const float den = __expf(-fmaxf(0.0f, dmn));                        \
            const float hv  = (mjn == mj) ? h_row : s_ht[mjn * H + h];          \
            s_inp[h] = den * hv;                                                \
        }                                                                       \
        BARRIER();  /* A: s_inp + h_t ready */                                  \
    }

    int j = 0;
    while (j < len) {
        STEP(A0, A1, A2, A3, AH, B0, B1, B2, B3, BH); ++j;
        if (j >= len) break;
        STEP(B0, B1, B2, B3, BH, A0, A1, A2, A3, AH); ++j;
    }
    #undef STEP
    #undef DOTF
    #undef ISSUE5

    // drain the dangling prefetch before its regs can be reallocated
    asm volatile("s_waitcnt vmcnt(0) lgkmcnt(0)" ::: "memory");
    __syncthreads();

    // ---- epilogue ----
    if (tid < H) s_ct[tid] = c_t;
    __syncthreads();

    float z0 = 0.0f, z1 = 0.0f;
    for (int i = tid; i < FEATS; i += NTH) {
        const float f = s_feats[i];
        const float2 w = *(const float2*)(W_out + 2 * i);
        z0 = fmaf(f, w.x, z0);
        z1 = fmaf(f, w.y, z1);
    }
    #pragma unroll
    for (int off = 32; off > 0; off >>= 1) {
        z0 += __shfl_down(z0, off, 64);
        z1 += __shfl_down(z1, off, 64);
    }
    const int wave = tid >> 6, lane = tid & 63;
    if (lane == 0) { s_red[2 * wave] = z0; s_red[2 * wave + 1] = z1; }
    __syncthreads();
    if (tid == 0) {
        float a0 = b_out[0], a1 = b_out[1];
        #pragma unroll
        for (int w = 0; w < 16; ++w) { a0 += s_red[2 * w]; a1 += s_red[2 * w + 1]; }
        const float mx = fmaxf(a0, a1);
        const float e0 = __expf(a0 - mx), e1 = __expf(a1 - mx);
        const float inv = 1.0f / (e0 + e1);
        out[2 * b]     = e0 * inv;
        out[2 * b + 1] = e1 * inv;
    }
}

// ---------------- fp32 fallback (no-workspace path) ----------------
#define NTHREADS 512
__global__ __launch_bounds__(NTHREADS)
void lstm_scan_kernel(const float* __restrict__ X,
                      const int* __restrict__ lengths,
                      const float* __restrict__ W_lin,
                      const float* __restrict__ b_lin,
                      const float* __restrict__ W_dec,
                      const float* __restrict__ b_dec,
                      const float* __restrict__ W_out,
                      const float* __restrict__ b_out,
                      float* __restrict__ out)
{
    __shared__ float s_feats[FEATS];
    __shared__ float s_inp[H];
    __shared__ float s_part[4][H4];
    __shared__ float s_X[4 * T];
    __shared__ float s_wdec[NF];
    __shared__ float s_bdec[NF];
    __shared__ float s_red[16];

    float* s_ct = s_feats;
    float* s_ht = s_feats + H;

    const int tid = threadIdx.x;
    const int b   = blockIdx.x;
    const int g4  = tid & 127;
    const int kq  = tid >> 7;

    const float* Xb = X + b * 4 * T;
    const int len = lengths[b];

    for (int i = tid; i < NF * H; i += NTHREADS) s_ht[i] = 0.0f;
    for (int i = tid; i < 4 * T; i += NTHREADS) s_X[i] = Xb[i];
    if (tid < NF) { s_wdec[tid] = W_dec[tid]; s_bdec[tid] = b_dec[tid]; }
    __syncthreads();

    float c_t = 0.0f, acc = 0.0f, cnt = 0.0f;

    for (int j = 0; j < len; ++j) {
        const int   mj = (int)s_X[T + j];
        const float xj = s_X[2 * T + j];
        const float* Wf = W_lin + mj * WF_STRIDE;

        float bl0, bl1, bl2, bl3;
        if (tid < H) {
            const float dj    = s_X[3 * T + j];
            const float dm    = fmaf(s_wdec[mj], dj, s_bdec[mj]);
            const float decay = __expf(-fmaxf(0.0f, dm));
            s_inp[tid] = decay * s_ht[mj * H + tid];
            const int m4 = mj * H4;
            bl0 = b_lin[m4 + tid];
            bl1 = b_lin[m4 + H + tid];
            bl2 = b_lin[m4 + 2 * H + tid];
            bl3 = b_lin[m4 + 3 * H + tid];
        }
        __syncthreads();

        float4 a4 = make_float4(0.0f, 0.0f, 0.0f, 0.0f);
        {
            const float*  wr  = Wf + (1 + kq * 32) * H4 + 4 * g4;
            const float4* ivp = (const float4*)(s_inp + kq * 32);
            #pragma unroll
            for (int cc = 0; cc < 8; ++cc) {
                const float4 v = ivp[cc];
                const float* wrc = wr + (4 * cc) * H4;
                const float4 w0 = *(const float4*)(wrc);
                const float4 w1 = *(const float4*)(wrc + H4);
                const float4 w2 = *(const float4*)(wrc + 2 * H4);
                const float4 w3 = *(const float4*)(wrc + 3 * H4);
                a4.x = fmaf(v.x, w0.x, a4.x); a4.y = fmaf(v.x, w0.y, a4.y);
                a4.z = fmaf(v.x, w0.z, a4.z); a4.w = fmaf(v.x, w0.w, a4.w);
                a4.x = fmaf(v.y, w1.x, a4.x); a4.y = fmaf(v.y, w1.y, a4.y);
                a4.z = fmaf(v.y, w1.z, a4.z); a4.w = fmaf(v.y, w1.w, a4.w);
                a4.x = fmaf(v.z, w2.x, a4.x); a4.y = fmaf(v.z, w2.y, a4.y);
                a4.z = fmaf(v.z, w2.z, a4.z); a4.w = fmaf(v.z, w2.w, a4.w);
                a4.x = fmaf(v.w, w3.x, a4.x); a4.y = fmaf(v.w, w3.y, a4.y);
                a4.z = fmaf(v.w, w3.z, a4.z); a4.w = fmaf(v.w, w3.w, a4.w);
            }
        }
        if (kq == 0) {
            const float4 wv = *(const float4*)(Wf + 4 * g4);
            a4.x = fmaf(xj, wv.x, a4.x); a4.y = fmaf(xj, wv.y, a4.y);
            a4.z = fmaf(xj, wv.z, a4.z); a4.w = fmaf(xj, wv.w, a4.w);
        }
        *(float4*)(&s_part[kq][4 * g4]) = a4;
        __syncthreads();

        if (tid < H) {
            const int h = tid;
            const float gi = s_part[0][h]         + s_part[1][h]         + s_part[2][h]         + s_part[3][h]         + bl0;
            const float gf = s_part[0][H + h]     + s_part[1][H + h]     + s_part[2][H + h]     + s_part[3][H + h]     + bl1;
            const float go = s_part[0][2*H + h]   + s_part[1][2*H + h]   + s_part[2][2*H + h]   + s_part[3][2*H + h]   + bl2;
            const float gc = s_part[0][3*H + h]   + s_part[1][3*H + h]   + s_part[2][3*H + h]   + s_part[3][3*H + h]   + bl3;

            const float c_cand = sigmoidf_(gf) * c_t + sigmoidf_(gi) * tanhf_(gc);
            const float h_row  = sigmoidf_(go) * tanhf_(c_cand);
            s_ht[mj * H + h] = h_row;
            acc += c_cand;
            cnt += 1.0f;

            const float tj = s_X[j];
            const float tn = (j < T - 1) ? s_X[j + 1] : (tj + 1.0f);
            const bool boundary = (j == len - 1) || (tn != tj);
            if (boundary) { c_t = acc / fmaxf(cnt, 1.0f); acc = 0.0f; cnt = 0.0f; }
        }
        __syncthreads();
    }

    if (tid < H) s_ct[tid] = c_t;
    __syncthreads();

    float z0 = 0.0f, z1 = 0.0f;
    for (int i = tid; i < FEATS; i += NTHREADS) {
        const float f = s_feats[i];
        const float2 wv = *(const float2*)(W_out + 2 * i);
        z0 = fmaf(f, wv.x, z0);
        z1 = fmaf(f, wv.y, z1);
    }
    #pragma unroll
    for (int off = 32; off > 0; off >>= 1) {
        z0 += __shfl_down(z0, off, 64);
        z1 += __shfl_down(z1, off, 64);
    }
    const int wave = tid >> 6, lane = tid & 63;
    if (lane == 0) { s_red[2 * wave] = z0; s_red[2 * wave + 1] = z1; }
    __syncthreads();
    if (tid == 0) {
        float a0 = b_out[0], a1 = b_out[1];
        #pragma unroll
        for (int q = 0; q < 8; ++q) { a0 += s_red[2 * q]; a1 += s_red[2 * q + 1]; }
        const float mx = fmaxf(a0, a1);
        const float e0 = __expf(a0 - mx), e1 = __expf(a1 - mx);
        const float inv = 1.0f / (e0 + e1);
        out[2 * b]     = e0 * inv;
        out[2 * b + 1] = e1 * inv;
    }
}

extern "C" void kernel_launch(void* const* d_in, const int* in_sizes, int n_in,
                              void* d_out, int out_size, void* d_ws, size_t ws_size,
                              hipStream_t stream) {
    const float* X      = (const float*)d_in[0];
    const int*   lens   = (const int*)d_in[1];
    const float* W_lin  = (const float*)d_in[2];
    const float* b_lin  = (const float*)d_in[3];
    const float* W_dec  = (const float*)d_in[4];
    const float* b_dec  = (const float*)d_in[5];
    const float* W_out  = (const float*)d_in[6];
    const float* b_out  = (const float*)d_in[7];
    float* out = (float*)d_out;

    if (ws_size >= REC_BYTES) {
        uint4* rec = (uint4*)d_ws;
        hipLaunchKernelGGL(repack5_kernel, dim3(NF * 1024 / 256), dim3(256), 0, stream,
                           W_lin, b_lin, rec);
        hipLaunchKernelGGL(lstm_scan_fp8_v3, dim3(BATCH), dim3(NTH), 0, stream,
                           X, lens, W_dec, b_dec, W_out, b_out, rec, out);
    } else {
        hipLaunchKernelGGL(lstm_scan_kernel, dim3(BATCH), dim3(NTHREADS), 0, stream,
                           X, lens, W_lin, b_lin, W_dec, b_dec, W_out, b_out, out);
    }
}

// Round 13
// 448.684 us; speedup vs baseline: 1.0213x; 1.0213x over previous
//
#include <hip/hip_runtime.h>
#include <math.h>
#include <stdint.h>

#define BATCH 64
#define T 256
#define NF 64
#define H 128
#define H4 512                    // 4*H
#define HP1 129
#define WF_STRIDE (HP1 * H4)      // 66048 floats per feature
#define FEATS (NF * H + H)        // 8320
#define NTH 1024                  // 16 waves

// pack: uint4 idx = (f*4 + i)*1024 + t  (4 MB), col = i*128 + (t&127),
//       k = (t>>7)*16 + 4w + r  -> fp8(W[f][1+k][col] * 4096)
#define PACK_U4 (NF * 4 * 1024)
#define PACK_BYTES ((size_t)PACK_U4 * 16u)            // 4 MB
// aux: float4 idx = f*1024 + t : kq==0 -> wx[col(i)], kq==1 -> bias[col(i)], else 0
#define AUX_BYTES ((size_t)NF * 1024 * 16u)           // 1 MB
#define WS_NEED (PACK_BYTES + AUX_BYTES)              // 5 MB

typedef float vf2 __attribute__((ext_vector_type(2)));

__device__ __forceinline__ float sigmoidf_(float x) {
    return 1.0f / (1.0f + __expf(-x));
}

__device__ __forceinline__ float tanhf_(float x) {
    float ax = fabsf(x);
    float e = __expf(2.0f * ax);              // inf for large ax -> r = 1
    float r = 1.0f - 2.0f / (e + 1.0f);
    return copysignf(r, x);
}

// decode 2 fp8 bytes of a dword -> float2 (HI must be literal)
template<bool HI>
__device__ __forceinline__ vf2 dec2f(unsigned u) {
    return __builtin_amdgcn_cvt_pk_f32_fp8(u, HI);
}

// ===== repack: fp8 x4096, 4-cols-per-thread layout =========================
__global__ __launch_bounds__(256)
void repack6_kernel(const float* __restrict__ W_lin, uint4* __restrict__ pack) {
    const int lin = blockIdx.x * 256 + threadIdx.x;   // 0..262143
    const int t   = lin & 1023;
    const int i   = (lin >> 10) & 3;
    const int f   = lin >> 12;
    const int kq  = t >> 7;
    const int cg  = t & 127;
    const int col = i * 128 + cg;
    unsigned u[4];
    #pragma unroll
    for (int w = 0; w < 4; ++w) {
        const float* src = W_lin + (size_t)f * WF_STRIDE
                         + (size_t)(1 + kq * 16 + 4 * w) * H4 + col;
        const float v0 = src[0]      * 4096.0f;
        const float v1 = src[H4]     * 4096.0f;
        const float v2 = src[2 * H4] * 4096.0f;
        const float v3 = src[3 * H4] * 4096.0f;
        unsigned r = 0;
        r = __builtin_amdgcn_cvt_pk_fp8_f32(v0, v1, r, false);
        r = __builtin_amdgcn_cvt_pk_fp8_f32(v2, v3, r, true);
        u[w] = r;
    }
    uint4 o; o.x = u[0]; o.y = u[1]; o.z = u[2]; o.w = u[3];
    pack[lin] = o;
}

// aux[f*1024 + t] = float4: kq==0 -> x-row W[f][0][col(i)], kq==1 -> bias, else 0
__global__ __launch_bounds__(256)
void aux6_kernel(const float* __restrict__ W_lin, const float* __restrict__ b_lin,
                 float4* __restrict__ aux) {
    const int lin = blockIdx.x * 256 + threadIdx.x;   // 0..65535
    const int t   = lin & 1023;
    const int f   = lin >> 10;
    const int kq  = t >> 7;
    const int cg  = t & 127;
    float4 o = make_float4(0.f, 0.f, 0.f, 0.f);
    if (kq == 0) {
        o.x = W_lin[(size_t)f * WF_STRIDE + cg];
        o.y = W_lin[(size_t)f * WF_STRIDE + 128 + cg];
        o.z = W_lin[(size_t)f * WF_STRIDE + 256 + cg];
        o.w = W_lin[(size_t)f * WF_STRIDE + 384 + cg];
    } else if (kq == 1) {
        o.x = b_lin[f * H4 + cg];
        o.y = b_lin[f * H4 + 128 + cg];
        o.z = b_lin[f * H4 + 256 + cg];
        o.w = b_lin[f * H4 + 384 + cg];
    }
    aux[lin] = o;
}

// ===== main scan: R11 skeleton, 4 cols x 16 k's per thread ==================
// Same VALU count as R11 (64 MACs/thread) but input LDS reads drop 4x
// (4 ds_read_b128 vs 16): the input-broadcast traffic (~256 b128 insts/CU/step)
// was the largest unattacked step cost. aux (f32 wx/bias) folds the x-term and
// bias into the K-partials, keeping absmax at 0 (R12's fp16 bias regressed it).
__global__ __launch_bounds__(NTH, 2)
void lstm_scan_fp8_v4(const float* __restrict__ X,
                      const int* __restrict__ lengths,
                      const float* __restrict__ W_dec,
                      const float* __restrict__ b_dec,
                      const float* __restrict__ W_out,
                      const float* __restrict__ b_out,
                      const uint4* __restrict__ pack,
                      const float4* __restrict__ aux,
                      float* __restrict__ out)
{
    __shared__ float s_feats[FEATS];          // [0,H)=c_t, [H,..)=h_t row-major
    __shared__ float s_inp[H];                // decayed hidden row (f32)
    __shared__ float s_part[8][H4];           // 8-way K-split partials (16 KB)
    __shared__ float s_X[4 * T];
    __shared__ float s_wdec[NF];
    __shared__ float s_bdec[NF];
    __shared__ float s_red[32];

    float* s_ct = s_feats;
    float* s_ht = s_feats + H;

    const int tid = threadIdx.x;
    const int b   = blockIdx.x;
    const int cg  = tid & 127;                // column within gate
    const int kq  = tid >> 7;                 // K chunk 0..7 (wave-uniform)

    const float* Xb = X + b * 4 * T;
    const int len = lengths[b];

    for (int i = tid; i < NF * H; i += NTH) s_ht[i] = 0.0f;
    for (int i = tid; i < 4 * T; i += NTH) s_X[i] = Xb[i];
    if (tid < NF) { s_wdec[tid] = W_dec[tid]; s_bdec[tid] = b_dec[tid]; }
    if (tid < H) s_inp[tid] = 0.0f;
    __syncthreads();

    float c_t = 0.0f, accs = 0.0f, cnts = 0.0f;

    // dot of one weight-uint4 (16 fp8 k's of one column) vs iv8[0..7]
    #define DOTC(W, ACC) do {                                                   \
        vf2 d;                                                                  \
        d = dec2f<false>((W).x); ACC += d * iv8[0];                             \
        d = dec2f<true >((W).x); ACC += d * iv8[1];                             \
        d = dec2f<false>((W).y); ACC += d * iv8[2];                             \
        d = dec2f<true >((W).y); ACC += d * iv8[3];                             \
        d = dec2f<false>((W).z); ACC += d * iv8[4];                             \
        d = dec2f<true >((W).z); ACC += d * iv8[5];                             \
        d = dec2f<false>((W).w); ACC += d * iv8[6];                             \
        d = dec2f<true >((W).w); ACC += d * iv8[7];                             \
    } while (0)

    uint4 A0, A1, A2, A3, B0, B1, B2, B3;
    float4 AX = make_float4(0.f, 0.f, 0.f, 0.f), BX = AX;

    // prologue: prefetch step 0
    {
        const int m0 = (int)s_X[T];
        const uint4* p0 = pack + (size_t)m0 * 4096 + tid;
        A0 = p0[0]; A1 = p0[1024]; A2 = p0[2048]; A3 = p0[3072];
        AX = aux[(size_t)m0 * 1024 + tid];
    }

    #define STEP(C0, C1, C2, C3, CX, N0, N1, N2, N3, NX)                        \
    {                                                                           \
        const int   mj  = (int)s_X[T + j];                                      \
        const float xj  = s_X[2 * T + j];                                       \
        const int   jn  = (j + 1 < T) ? (j + 1) : (T - 1);                      \
        const int   mjn = (int)s_X[T + jn];                                     \
        /* prefetch next step (consumed NEXT iteration) */                      \
        {                                                                       \
            const uint4* pn = pack + (size_t)mjn * 4096 + tid;                  \
            N0 = pn[0]; N1 = pn[1024]; N2 = pn[2048]; N3 = pn[3072];            \
            NX = aux[(size_t)mjn * 1024 + tid];                                 \
        }                                                                       \
        /* input slice: 16 f32 (4 ds_read_b128, wave-uniform -> broadcast) */   \
        vf2 iv8[8];                                                             \
        {                                                                       \
            const float4* ip = (const float4*)(s_inp + kq * 16);                \
            _Pragma("unroll")                                                   \
            for (int q = 0; q < 4; ++q) {                                       \
                const float4 t_ = ip[q];                                        \
                iv8[2 * q][0] = t_.x;     iv8[2 * q][1] = t_.y;                 \
                iv8[2 * q + 1][0] = t_.z; iv8[2 * q + 1][1] = t_.w;             \
            }                                                                   \
        }                                                                       \
        vf2 ac0, ac1, ac2, ac3;                                                 \
        ac0 = 0.0f; ac1 = 0.0f; ac2 = 0.0f; ac3 = 0.0f;                         \
        DOTC(C0, ac0); DOTC(C1, ac1); DOTC(C2, ac2); DOTC(C3, ac3);             \
        float a0 = (ac0[0] + ac0[1]) * (1.0f / 4096.0f);                        \
        float a1 = (ac1[0] + ac1[1]) * (1.0f / 4096.0f);                        \
        float a2 = (ac2[0] + ac2[1]) * (1.0f / 4096.0f);                        \
        float a3 = (ac3[0] + ac3[1]) * (1.0f / 4096.0f);                        \
        if (kq == 0) {                                                          \
            a0 = fmaf(xj, CX.x, a0); a1 = fmaf(xj, CX.y, a1);                   \
            a2 = fmaf(xj, CX.z, a2); a3 = fmaf(xj, CX.w, a3);                   \
        } else if (kq == 1) {                                                   \
            a0 += CX.x; a1 += CX.y; a2 += CX.z; a3 += CX.w;                     \
        }                                                                       \
        s_part[kq][cg]       = a0;                                              \
        s_part[kq][128 + cg] = a1;                                              \
        s_part[kq][256 + cg] = a2;                                              \
        s_part[kq][384 + cg] = a3;                                              \
        __syncthreads();  /* B: partials ready */                               \
        if (tid < H) {                                                          \
            const int h = tid;                                                  \
            float g0 = 0.f, g1 = 0.f, g2 = 0.f, g3 = 0.f;                       \
            _Pragma("unroll")                                                   \
            for (int q = 0; q < 8; ++q) {                                       \
                g0 += s_part[q][h];                                             \
                g1 += s_part[q][128 + h];                                       \
                g2 += s_part[q][256 + h];                                       \
                g3 += s_part[q][384 + h];                                       \
            }                                                                   \
            const float c_cand = sigmoidf_(g1) * c_t + sigmoidf_(g0) * tanhf_(g3); \
            const float h_row  = sigmoidf_(g2) * tanhf_(c_cand);                \
            s_ht[mj * H + h] = h_row;                                           \
            accs += c_cand;                                                     \
            cnts += 1.0f;                                                       \
            const float tj = s_X[j];                                            \
            const float tn = (j < T - 1) ? s_X[j + 1] : (tj + 1.0f);            \
            const bool boundary = (j == len - 1) || (tn != tj);                 \
            if (boundary) { c_t = accs / fmaxf(cnts, 1.0f); accs = 0.0f; cnts = 0.0f; } \
            const float dn  = s_X[3 * T + jn];                                  \
            const float dmn = fmaf(s_wdec[mjn], dn, s_bdec[mjn]);               \
            const float den = __expf(-fmaxf(0.0f, dmn));                        \
            const float hv  = (mjn == mj) ? h_row : s_ht[mjn * H + h];          \
            s_inp[h] = den * hv;                                                \
        }                                                                       \
        __syncthreads();  /* A: s_inp + h_t ready */                            \
    }

    int j = 0;
    while (j < len) {
        STEP(A0, A1, A2, A3, AX, B0, B1, B2, B3, BX); ++j;
        if (j >= len) break;
        STEP(B0, B1, B2, B3, BX, A0, A1, A2, A3, AX); ++j;
    }
    #undef STEP
    #undef DOTC

    // ---- epilogue ----
    if (tid < H) s_ct[tid] = c_t;
    __syncthreads();

    float z0 = 0.0f, z1 = 0.0f;
    for (int i = tid; i < FEATS; i += NTH) {
        const float f = s_feats[i];
        const float2 w = *(const float2*)(W_out + 2 * i);
        z0 = fmaf(f, w.x, z0);
        z1 = fmaf(f, w.y, z1);
    }
    #pragma unroll
    for (int off = 32; off > 0; off >>= 1) {
        z0 += __shfl_down(z0, off, 64);
        z1 += __shfl_down(z1, off, 64);
    }
    const int wave = tid >> 6, lane = tid & 63;
    if (lane == 0) { s_red[2 * wave] = z0; s_red[2 * wave + 1] = z1; }
    __syncthreads();
    if (tid == 0) {
        float a0 = b_out[0], a1 = b_out[1];
        #pragma unroll
        for (int w = 0; w < 16; ++w) { a0 += s_red[2 * w]; a1 += s_red[2 * w + 1]; }
        const float mx = fmaxf(a0, a1);
        const float e0 = __expf(a0 - mx), e1 = __expf(a1 - mx);
        const float inv = 1.0f / (e0 + e1);
        out[2 * b]     = e0 * inv;
        out[2 * b + 1] = e1 * inv;
    }
}

// ---------------- fp32 fallback (no-workspace path) ----------------
#define NTHREADS 512
__global__ __launch_bounds__(NTHREADS)
void lstm_scan_kernel(const float* __restrict__ X,
                      const int* __restrict__ lengths,
                      const float* __restrict__ W_lin,
                      const float* __restrict__ b_lin,
                      const float* __restrict__ W_dec,
                      const float* __restrict__ b_dec,
                      const float* __restrict__ W_out,
                      const float* __restrict__ b_out,
                      float* __restrict__ out)
{
    __shared__ float s_feats[FEATS];
    __shared__ float s_inp[H];
    __shared__ float s_part[4][H4];
    __shared__ float s_X[4 * T];
    __shared__ float s_wdec[NF];
    __shared__ float s_bdec[NF];
    __shared__ float s_red[16];

    float* s_ct = s_feats;
    float* s_ht = s_feats + H;

    const int tid = threadIdx.x;
    const int b   = blockIdx.x;
    const int g4  = tid & 127;
    const int kq  = tid >> 7;

    const float* Xb = X + b * 4 * T;
    const int len = lengths[b];

    for (int i = tid; i < NF * H; i += NTHREADS) s_ht[i] = 0.0f;
    for (int i = tid; i < 4 * T; i += NTHREADS) s_X[i] = Xb[i];
    if (tid < NF) { s_wdec[tid] = W_dec[tid]; s_bdec[tid] = b_dec[tid]; }
    __syncthreads();

    float c_t = 0.0f, acc = 0.0f, cnt = 0.0f;

    for (int j = 0; j < len; ++j) {
        const int   mj = (int)s_X[T + j];
        const float xj = s_X[2 * T + j];
        const float* Wf = W_lin + mj * WF_STRIDE;

        float bl0, bl1, bl2, bl3;
        if (tid < H) {
            const float dj    = s_X[3 * T + j];
            const float dm    = fmaf(s_wdec[mj], dj, s_bdec[mj]);
            const float decay = __expf(-fmaxf(0.0f, dm));
            s_inp[tid] = decay * s_ht[mj * H + tid];
            const int m4 = mj * H4;
            bl0 = b_lin[m4 + tid];
            bl1 = b_lin[m4 + H + tid];
            bl2 = b_lin[m4 + 2 * H + tid];
            bl3 = b_lin[m4 + 3 * H + tid];
        }
        __syncthreads();

        float4 a4 = make_float4(0.0f, 0.0f, 0.0f, 0.0f);
        {
            const float*  wr  = Wf + (1 + kq * 32) * H4 + 4 * g4;
            const float4* ivp = (const float4*)(s_inp + kq * 32);
            #pragma unroll
            for (int cc = 0; cc < 8; ++cc) {
                const float4 v = ivp[cc];
                const float* wrc = wr + (4 * cc) * H4;
                const float4 w0 = *(const float4*)(wrc);
                const float4 w1 = *(const float4*)(wrc + H4);
                const float4 w2 = *(const float4*)(wrc + 2 * H4);
                const float4 w3 = *(const float4*)(wrc + 3 * H4);
                a4.x = fmaf(v.x, w0.x, a4.x); a4.y = fmaf(v.x, w0.y, a4.y);
                a4.z = fmaf(v.x, w0.z, a4.z); a4.w = fmaf(v.x, w0.w, a4.w);
                a4.x = fmaf(v.y, w1.x, a4.x); a4.y = fmaf(v.y, w1.y, a4.y);
                a4.z = fmaf(v.y, w1.z, a4.z); a4.w = fmaf(v.y, w1.w, a4.w);
                a4.x = fmaf(v.z, w2.x, a4.x); a4.y = fmaf(v.z, w2.y, a4.y);
                a4.z = fmaf(v.z, w2.z, a4.z); a4.w = fmaf(v.z, w2.w, a4.w);
                a4.x = fmaf(v.w, w3.x, a4.x); a4.y = fmaf(v.w, w3.y, a4.y);
                a4.z = fmaf(v.w, w3.z, a4.z); a4.w = fmaf(v.w, w3.w, a4.w);
            }
        }
        if (kq == 0) {
            const float4 wv = *(const float4*)(Wf + 4 * g4);
            a4.x = fmaf(xj, wv.x, a4.x); a4.y = fmaf(xj, wv.y, a4.y);
            a4.z = fmaf(xj, wv.z, a4.z); a4.w = fmaf(xj, wv.w, a4.w);
        }
        *(float4*)(&s_part[kq][4 * g4]) = a4;
        __syncthreads();

        if (tid < H) {
            const int h = tid;
            const float gi = s_part[0][h]         + s_part[1][h]         + s_part[2][h]         + s_part[3][h]         + bl0;
            const float gf = s_part[0][H + h]     + s_part[1][H + h]     + s_part[2][H + h]     + s_part[3][H + h]     + bl1;
            const float go = s_part[0][2*H + h]   + s_part[1][2*H + h]   + s_part[2][2*H + h]   + s_part[3][2*H + h]   + bl2;
            const float gc = s_part[0][3*H + h]   + s_part[1][3*H + h]   + s_part[2][3*H + h]   + s_part[3][3*H + h]   + bl3;

            const float c_cand = sigmoidf_(gf) * c_t + sigmoidf_(gi) * tanhf_(gc);
            const float h_row  = sigmoidf_(go) * tanhf_(c_cand);
            s_ht[mj * H + h] = h_row;
            acc += c_cand;
            cnt += 1.0f;

            const float tj = s_X[j];
            const float tn = (j < T - 1) ? s_X[j + 1] : (tj + 1.0f);
            const bool boundary = (j == len - 1) || (tn != tj);
            if (boundary) { c_t = acc / fmaxf(cnt, 1.0f); acc = 0.0f; cnt = 0.0f; }
        }
        __syncthreads();
    }

    if (tid < H) s_ct[tid] = c_t;
    __syncthreads();

    float z0 = 0.0f, z1 = 0.0f;
    for (int i = tid; i < FEATS; i += NTHREADS) {
        const float f = s_feats[i];
        const float2 wv = *(const float2*)(W_out + 2 * i);
        z0 = fmaf(f, wv.x, z0);
        z1 = fmaf(f, wv.y, z1);
    }
    #pragma unroll
    for (int off = 32; off > 0; off >>= 1) {
        z0 += __shfl_down(z0, off, 64);
        z1 += __shfl_down(z1, off, 64);
    }
    const int wave = tid >> 6, lane = tid & 63;
    if (lane == 0) { s_red[2 * wave] = z0; s_red[2 * wave + 1] = z1; }
    __syncthreads();
    if (tid == 0) {
        float a0 = b_out[0], a1 = b_out[1];
        #pragma unroll
        for (int q = 0; q < 8; ++q) { a0 += s_red[2 * q]; a1 += s_red[2 * q + 1]; }
        const float mx = fmaxf(a0, a1);
        const float e0 = __expf(a0 - mx), e1 = __expf(a1 - mx);
        const float inv = 1.0f / (e0 + e1);
        out[2 * b]     = e0 * inv;
        out[2 * b + 1] = e1 * inv;
    }
}

extern "C" void kernel_launch(void* const* d_in, const int* in_sizes, int n_in,
                              void* d_out, int out_size, void* d_ws, size_t ws_size,
                              hipStream_t stream) {
    const float* X      = (const float*)d_in[0];
    const int*   lens   = (const int*)d_in[1];
    const float* W_lin  = (const float*)d_in[2];
    const float* b_lin  = (const float*)d_in[3];
    const float* W_dec  = (const float*)d_in[4];
    const float* b_dec  = (const float*)d_in[5];
    const float* W_out  = (const float*)d_in[6];
    const float* b_out  = (const float*)d_in[7];
    float* out = (float*)d_out;

    if (ws_size >= WS_NEED) {
        uint4*  pack = (uint4*)d_ws;
        float4* aux  = (float4*)((char*)d_ws + PACK_BYTES);
        hipLaunchKernelGGL(repack6_kernel, dim3(PACK_U4 / 256), dim3(256), 0, stream,
                           W_lin, pack);
        hipLaunchKernelGGL(aux6_kernel, dim3(NF * 1024 / 256), dim3(256), 0, stream,
                           W_lin, b_lin, aux);
        hipLaunchKernelGGL(lstm_scan_fp8_v4, dim3(BATCH), dim3(NTH), 0, stream,
                           X, lens, W_dec, b_dec, W_out, b_out, pack, aux, out);
    } else {
        hipLaunchKernelGGL(lstm_scan_kernel, dim3(BATCH), dim3(NTHREADS), 0, stream,
                           X, lens, W_lin, b_lin, W_dec, b_dec, W_out, b_out, out);
    }
}